// Round 2
// baseline (5223.144 us; speedup 1.0000x reference)
//
#include <hip/hip_runtime.h>
#include <hip/hip_bf16.h>
#include <cstdint>

// Problem constants
#define B_   64
#define T_   512
#define IN_  512
#define H_   1024
#define O_   512
#define NG   4096              // 4*H, gate-interleaved: n = 4*h + g  (g: 0=i,1=f,2=o,3=c)
#define KC   1536              // IN_ + H_ combined GEMM depth
#define BT   32768             // B*T
#define BH   65536             // B*H

using bs8 = __attribute__((ext_vector_type(8))) short;   // 8 x bf16 (4 VGPRs)
using f4  = __attribute__((ext_vector_type(4))) float;   // 4 x f32

__device__ __forceinline__ ushort f2bf(float f) {
    union { float f; uint32_t u; } v; v.f = f;
    uint32_t r = v.u + 0x7fffu + ((v.u >> 16) & 1u);   // round-to-nearest-even
    return (ushort)(r >> 16);
}
__device__ __forceinline__ float bf2f(ushort u) {
    union { uint32_t u; float f; } v; v.u = ((uint32_t)u) << 16;
    return v.f;
}
__device__ __forceinline__ float sigm(float x) { return 1.f / (1.f + __expf(-x)); }
__device__ __forceinline__ float tanh_(float x) {
    x = fminf(fmaxf(x, -15.f), 15.f);
    float e = __expf(2.f * x);
    return (e - 1.f) / (e + 1.f);
}

// ---------------- conversion / layout kernels ----------------

__global__ void k_cvt_x(const float* __restrict__ x, ushort* __restrict__ xbf) {
    const int n4 = BT * IN_ / 4;
    for (int i = blockIdx.x * blockDim.x + threadIdx.x; i < n4; i += gridDim.x * blockDim.x) {
        f4 v = *reinterpret_cast<const f4*>(x + (size_t)i * 4);
        uint32_t lo = (uint32_t)f2bf(v[0]) | ((uint32_t)f2bf(v[1]) << 16);
        uint32_t hi = (uint32_t)f2bf(v[2]) | ((uint32_t)f2bf(v[3]) << 16);
        uint2 p; p.x = lo; p.y = hi;
        *reinterpret_cast<uint2*>(xbf + (size_t)i * 4) = p;
    }
}

// WcT[n][k] (bf16), n = 4h+g; k<512 -> Wx_g[k][h], k>=512 -> Wh_g[k-512][h]
__global__ void k_build_wcT(const float* __restrict__ xi, const float* __restrict__ xf,
                            const float* __restrict__ xo, const float* __restrict__ xc,
                            const float* __restrict__ hi, const float* __restrict__ hf,
                            const float* __restrict__ ho, const float* __restrict__ hc,
                            ushort* __restrict__ dst) {
    const int total = NG * KC;
    for (int i = blockIdx.x * blockDim.x + threadIdx.x; i < total; i += gridDim.x * blockDim.x) {
        int n = i / KC, k = i - n * KC;
        int g = n & 3, h = n >> 2;
        float v;
        if (k < IN_) {
            const float* s = (g == 0) ? xi : ((g == 1) ? xf : ((g == 2) ? xo : xc));
            v = s[(size_t)k * H_ + h];
        } else {
            const float* s = (g == 0) ? hi : ((g == 1) ? hf : ((g == 2) ? ho : hc));
            v = s[(size_t)(k - IN_) * H_ + h];
        }
        dst[i] = f2bf(v);
    }
}

// WhyT[o][k] = W_hy[k][o]
__global__ void k_build_whyT(const float* __restrict__ w, ushort* __restrict__ dst) {
    const int total = O_ * H_;
    for (int i = blockIdx.x * blockDim.x + threadIdx.x; i < total; i += gridDim.x * blockDim.x) {
        int o = i >> 10, k = i & (H_ - 1);
        dst[i] = f2bf(w[(size_t)k * O_ + o]);
    }
}

__global__ void k_build_bias(const float* __restrict__ bi, const float* __restrict__ bff,
                             const float* __restrict__ bo, const float* __restrict__ bc,
                             float* __restrict__ dst) {
    int i = blockIdx.x * blockDim.x + threadIdx.x;
    if (i < NG) {
        int g = i & 3, h = i >> 2;
        dst[i] = (g == 0) ? bi[h] : ((g == 1) ? bff[h] : ((g == 2) ? bo[h] : bc[h]));
    }
}

// ---------------- fused LSTM step ----------------
// gates[n][b] = WcT[n][:] . [x_t | h_prev][b][:]  (K=1536), then elementwise.
// 4 waves split K; LDS reduce; wave w does elementwise for b-tile w.
// MFMA 16x16x32 C/D: col = lane&15, row = (lane>>4)*4 + j  [verified m89].
__global__ void __launch_bounds__(256) k_step(const ushort* __restrict__ WcT,
                                              const ushort* __restrict__ xbf, int t,
                                              const ushort* __restrict__ hprev,
                                              ushort* __restrict__ hnext,
                                              const float* __restrict__ biasc,
                                              float* __restrict__ cst) {
    __shared__ f4 part[4][4][64];     // [wave][b-tile][lane]
    const int lane = threadIdx.x & 63;
    const int w = threadIdx.x >> 6;
    const int n0 = blockIdx.x * 16;
    const int l15 = lane & 15, lk = (lane >> 4) * 8;

    f4 acc[4] = {};
    const ushort* ap = WcT + (size_t)(n0 + l15) * KC + lk;

    // x part: wave w covers kk = 4w .. 4w+3  (k = kk*32 + lk)
    {
        const ushort* bp[4];
#pragma unroll
        for (int n = 0; n < 4; ++n)
            bp[n] = xbf + ((size_t)(n * 16 + l15) * T_ + t) * IN_ + lk;
#pragma unroll
        for (int q = 0; q < 4; ++q) {
            const int kk = w * 4 + q;
            bs8 a = *reinterpret_cast<const bs8*>(ap + kk * 32);
            bs8 b[4];
#pragma unroll
            for (int n = 0; n < 4; ++n) b[n] = *reinterpret_cast<const bs8*>(bp[n] + kk * 32);
#pragma unroll
            for (int n = 0; n < 4; ++n)
                acc[n] = __builtin_amdgcn_mfma_f32_16x16x32_bf16(a, b[n], acc[n], 0, 0, 0);
        }
    }
    // h part: wave w covers kk = 8w .. 8w+7  (k = 512 + kk*32 + lk)
    {
        const ushort* ah = ap + IN_;
        const ushort* bp[4];
#pragma unroll
        for (int n = 0; n < 4; ++n)
            bp[n] = hprev + (size_t)(n * 16 + l15) * H_ + lk;
#pragma unroll
        for (int q = 0; q < 8; ++q) {
            const int kk = w * 8 + q;
            bs8 a = *reinterpret_cast<const bs8*>(ah + kk * 32);
            bs8 b[4];
#pragma unroll
            for (int n = 0; n < 4; ++n) b[n] = *reinterpret_cast<const bs8*>(bp[n] + kk * 32);
#pragma unroll
            for (int n = 0; n < 4; ++n)
                acc[n] = __builtin_amdgcn_mfma_f32_16x16x32_bf16(a, b[n], acc[n], 0, 0, 0);
        }
    }

#pragma unroll
    for (int n = 0; n < 4; ++n) part[w][n][lane] = acc[n];
    __syncthreads();

    // wave w finishes b-tile n=w: reduce 4 partials, elementwise, write h/c
    f4 s = part[0][w][lane] + part[1][w][lane] + part[2][w][lane] + part[3][w][lane];
    const int nb = n0 + (lane >> 4) * 4;     // 4h aligned: gates j=0..3 (i,f,o,c)
    const int h = nb >> 2;
    const int b_ = w * 16 + l15;
    const f4 bia = *reinterpret_cast<const f4*>(biasc + nb);
    float pi = s[0] + bia[0];
    float pf = s[1] + bia[1];
    float po = s[2] + bia[2];
    float pc = s[3] + bia[3];
    float iv = sigm(pi), fv = sigm(pf), ov = sigm(po), cv = tanh_(pc);
    float co = cst[(size_t)b_ * H_ + h];
    float cn = fv * co + iv * cv;
    float hn = ov * tanh_(cn);
    cst[(size_t)b_ * H_ + h] = cn;
    hnext[(size_t)b_ * H_ + h] = f2bf(hn);
}

// ---------------- output projection ----------------
// y[b][t][o] = hsn[r][:] . W_hy[:,o] + b_y[o],  r = t_local*64 + b, t = t_off + t_local
__global__ void __launch_bounds__(64) k_yproj(const ushort* __restrict__ WhyT,
                                              const ushort* __restrict__ hsn,
                                              const float* __restrict__ by,
                                              float* __restrict__ out, int t_off) {
    const int lane = threadIdx.x;
    const int r0 = blockIdx.x * 64;
    const int o0 = blockIdx.y * 64;
    const int l15 = lane & 15, lk = (lane >> 4) * 8;

    const ushort* apm[4]; const ushort* bp[4];
#pragma unroll
    for (int m = 0; m < 4; ++m) apm[m] = WhyT + (size_t)(o0 + m * 16 + l15) * H_ + lk;
#pragma unroll
    for (int n = 0; n < 4; ++n) bp[n] = hsn + (size_t)(r0 + n * 16 + l15) * H_ + lk;

    f4 acc[4][4] = {};
    for (int kk = 0; kk < H_ / 32; ++kk) {
        bs8 a[4], b[4];
#pragma unroll
        for (int m = 0; m < 4; ++m) a[m] = *reinterpret_cast<const bs8*>(apm[m] + kk * 32);
#pragma unroll
        for (int n = 0; n < 4; ++n) b[n] = *reinterpret_cast<const bs8*>(bp[n] + kk * 32);
#pragma unroll
        for (int m = 0; m < 4; ++m)
#pragma unroll
            for (int n = 0; n < 4; ++n)
                acc[m][n] = __builtin_amdgcn_mfma_f32_16x16x32_bf16(a[m], b[n], acc[m][n], 0, 0, 0);
    }

#pragma unroll
    for (int m = 0; m < 4; ++m) {
        const int ob = o0 + m * 16 + (lane >> 4) * 4;
        const f4 bb = *reinterpret_cast<const f4*>(by + ob);
#pragma unroll
        for (int n = 0; n < 4; ++n) {
            const int r = r0 + n * 16 + l15;
            const int t = t_off + (r >> 6), b_ = r & 63;
            f4 v = acc[m][n] + bb;
            *reinterpret_cast<f4*>(out + ((size_t)b_ * T_ + t) * O_ + ob) = v;
        }
    }
}

// ---------------- launch ----------------

extern "C" void kernel_launch(void* const* d_in, const int* in_sizes, int n_in,
                              void* d_out, int out_size, void* d_ws, size_t ws_size,
                              hipStream_t stream) {
    const float* x   = (const float*)d_in[0];
    const float* wxi = (const float*)d_in[1];
    const float* whi = (const float*)d_in[2];
    const float* bi  = (const float*)d_in[3];
    const float* wxf = (const float*)d_in[4];
    const float* whf = (const float*)d_in[5];
    const float* bf_ = (const float*)d_in[6];
    const float* wxo = (const float*)d_in[7];
    const float* who = (const float*)d_in[8];
    const float* bo  = (const float*)d_in[9];
    const float* wxc = (const float*)d_in[10];
    const float* whc = (const float*)d_in[11];
    const float* bc  = (const float*)d_in[12];
    const float* why = (const float*)d_in[13];
    const float* by  = (const float*)d_in[14];
    float* out = (float*)d_out;

    // workspace layout (bytes); common prefix for both tiers
    uint8_t* w = (uint8_t*)d_ws;
    ushort* xbf   = (ushort*)(w);                     // 33,554,432
    ushort* WcT   = (ushort*)(w + 33554432);          // 12,582,912
    ushort* WhyT  = (ushort*)(w + 46137344);          //  1,048,576
    float*  biasc = (float*) (w + 47185920);          //     16,384
    float*  cst   = (float*) (w + 47202304);          //    262,144
    ushort* hs    = (ushort*)(w + 47464448);          // tier-dependent
    const size_t NEED_A = 47464448 + (size_t)(T_ + 1) * BH * 2;  // 114,704,384
    const size_t NEED_B = 47464448 + (size_t)65 * BH * 2;        //  55,984,128
    if (ws_size < NEED_B) return;   // cannot run
    const bool fullhs = (ws_size >= NEED_A);

    // 1) conversions / packed-weight builds (one-time per call, parallel)
    k_cvt_x<<<2048, 256, 0, stream>>>(x, xbf);
    k_build_wcT<<<4096, 256, 0, stream>>>(wxi, wxf, wxo, wxc, whi, whf, who, whc, WcT);
    k_build_whyT<<<512, 256, 0, stream>>>(why, WhyT);
    k_build_bias<<<16, 256, 0, stream>>>(bi, bf_, bo, bc, biasc);

    // 2) state init: c = 0, h_0 = 0
    hipMemsetAsync(cst, 0, (size_t)BH * 4, stream);
    hipMemsetAsync(hs,  0, (size_t)BH * 2, stream);

    if (fullhs) {
        // 3) 512 sequential fused steps, full h history
        for (int t = 0; t < T_; ++t)
            k_step<<<NG / 16, 256, 0, stream>>>(WcT, xbf, t, hs + (size_t)t * BH,
                                                hs + (size_t)(t + 1) * BH, biasc, cst);
        // 4) one output projection over all timesteps
        k_yproj<<<dim3(BT / 64, O_ / 64), 64, 0, stream>>>(WhyT, hs + BH, by, out, 0);
    } else {
        // ring of 65 h-slots; per-64-step chunked y projection
        for (int c = 0; c < T_ / 64; ++c) {
            for (int j = 0; j < 64; ++j) {
                const int t = c * 64 + j;
                k_step<<<NG / 16, 256, 0, stream>>>(WcT, xbf, t, hs + (size_t)j * BH,
                                                    hs + (size_t)(j + 1) * BH, biasc, cst);
            }
            k_yproj<<<dim3(64, O_ / 64), 64, 0, stream>>>(WhyT, hs + BH, by, out, c * 64);
            hipMemcpyAsync(hs, hs + (size_t)64 * BH, (size_t)BH * 2,
                           hipMemcpyDeviceToDevice, stream);
        }
    }
}